// Round 2
// baseline (472.874 us; speedup 1.0000x reference)
//
#include <hip/hip_runtime.h>
#include <math.h>

#define NK 512                      // N_EMB
#define NPTS (32*64*64)             // 131072 points
#define NELEM (32*64*64*64)         // 8388608 elements of z

// flat d_out offsets (return order: loss, z_q, perplexity, encodings, codebook)
#define OFF_LOSS 0
#define OFF_ZQ   1
#define OFF_PERP (1 + NELEM)
#define OFF_ENC  (2 + NELEM)
#define OFF_CB   (2 + NELEM + (size_t)NPTS * NK)

typedef float nt4 __attribute__((ext_vector_type(4)));   // native vec for nontemporal

// ws layout: [0,2048) hist int[512] | [2048,2056) lossAcc double |
//            [4096, +128KB) wT f32[64][512] | then bnd f32[512]

// ---- prep: wT[d][k] = w[k][d]; bnd[k] = sum_d w[k][d]^2 (sequential d) ----
__global__ __launch_bounds__(256) void vq_prep(const float* __restrict__ wg,
                                               float* __restrict__ wT,
                                               float* __restrict__ bnd) {
    __shared__ float tl[64 * 65];
    const int t = threadIdx.x;
    const int kbase = blockIdx.x * 64;          // 8 blocks x 64 codes
    #pragma unroll
    for (int it = 0; it < 16; ++it) {
        int i = it * 256 + t;
        int k = i >> 6, d = i & 63;
        tl[k * 65 + d] = wg[(size_t)(kbase + k) * 64 + d];
    }
    __syncthreads();
    #pragma unroll
    for (int it = 0; it < 16; ++it) {
        int j = it * 256 + t;
        int d = j >> 6, kk = j & 63;
        wT[(size_t)d * 512 + kbase + kk] = tl[kk * 65 + d];
    }
    if (t < 64) {
        float s = 0.f;
        #pragma unroll 4
        for (int d = 0; d < 64; ++d) {
            float v = tl[t * 65 + d];
            s = __fadd_rn(s, __fmul_rn(v, v));
        }
        bnd[kbase + t] = s;
    }
}

// block = 64 points (one b,h row); 256 threads = 8 pgroups x 32 cgroups.
// w is NOT staged in LDS: per-d each wave reads a contiguous 256B window of
// wT (L2-resident, 8-way lane broadcast coalesced). LDS = zt(16K) + 16K
// overlay + ~3K -> 4 blocks/CU (16 waves/CU), chunk loop is barrier-free.
__global__ __launch_bounds__(256, 4) void vq_main(const float* __restrict__ zg,
                                                  const float* __restrict__ wg,
                                                  const float* __restrict__ wT,
                                                  const float* __restrict__ bndg,
                                                  float* __restrict__ out,
                                                  int* __restrict__ hist,
                                                  double* __restrict__ lossAcc) {
    const int t = threadIdx.x;
    const int blk = blockIdx.x;          // 2048 blocks = (b,h)
    const int b = blk >> 6;
    const int h = blk & 63;

    __shared__ __align__(16) float zt[64 * 64];    // zt[d][p]   (16 KB)
    __shared__ __align__(16) float buf[4096];      // 16 KB overlay
    __shared__ __align__(16) float r2v[256];       // level-2 argmin vals
    __shared__ int   r2i[256];                     // level-2 argmin idxs
    __shared__ float aRow[64];                     // ||z_p||^2
    __shared__ int   idxs[64];                     // winning code per point
    __shared__ float wsum[4];                      // per-wave loss partials

    float* redv = buf;                      // [32][64]  (phase 1)
    int*   redi = (int*)(buf + 2048);       // [32][64]  (phase 1)
    float* zqt  = buf;                      // [64][64]  (phase 2, after barrier)

    // ---- stage z tile: zt[c][w] = z[b,c,h,w]  (float2, conflict-free) ----
    {
        const size_t base = (size_t)b * 262144 + (size_t)h * 64;
        const int w2 = (t & 31) * 2;
        const int c0 = t >> 5;                       // 0..7
        #pragma unroll
        for (int c = c0; c < 64; c += 8) {
            float2 v = *(const float2*)(zg + base + (size_t)c * 4096 + w2);
            *(float2*)(zt + c * 64 + w2) = v;
        }
    }
    __syncthreads();

    // ---- a_p = sum_d z^2 (sequential d, mul+add — matches reference) ----
    if (t < 64) {
        float s = 0.f;
        for (int d = 0; d < 64; ++d) {
            float v = zt[d * 64 + t];
            s = __fadd_rn(s, __fmul_rn(v, v));
        }
        aRow[t] = s;
    }
    __syncthreads();

    const int tx = t & 7;      // point group: p = tx*8 + i   (i < 8)
    const int ty = t >> 3;     // code group:  k = c*256 + ty*8 + j  (j < 8)
    const int p0 = tx * 8;
    const int k0 = ty * 8;

    float best[8];
    int bidx[8];
    #pragma unroll
    for (int i = 0; i < 8; ++i) { best[i] = INFINITY; bidx[i] = 0; }

    const float* ztp = zt + p0;

    #pragma unroll
    for (int c = 0; c < 2; ++c) {
        float acc[8][8];
        #pragma unroll
        for (int i = 0; i < 8; ++i)
            #pragma unroll
            for (int j = 0; j < 8; ++j) acc[i][j] = 0.f;

        const float* wrow = wT + c * 256 + k0;       // stride 512 floats per d

        #pragma unroll 4
        for (int d = 0; d < 64; ++d) {
            float4 z0 = *(const float4*)(ztp + d * 64);
            float4 z1 = *(const float4*)(ztp + d * 64 + 4);
            float4 w0 = *(const float4*)(wrow + d * 512);
            float4 w1 = *(const float4*)(wrow + d * 512 + 4);
            const float zr[8] = {z0.x, z0.y, z0.z, z0.w, z1.x, z1.y, z1.z, z1.w};
            const float wr[8] = {w0.x, w0.y, w0.z, w0.w, w1.x, w1.y, w1.z, w1.w};
            #pragma unroll
            for (int i = 0; i < 8; ++i)
                #pragma unroll
                for (int j = 0; j < 8; ++j)
                    acc[i][j] = fmaf(zr[i], wr[j], acc[i][j]);
        }

        // code norms + point norms loaded late (keeps the hot loop lean)
        float bn[8];
        {
            const float4* bp = (const float4*)(bndg + c * 256 + k0);
            float4 b0 = bp[0], b1 = bp[1];
            bn[0] = b0.x; bn[1] = b0.y; bn[2] = b0.z; bn[3] = b0.w;
            bn[4] = b1.x; bn[5] = b1.y; bn[6] = b1.z; bn[7] = b1.w;
        }
        float av[8];
        {
            float4 a0 = *(const float4*)(aRow + p0);
            float4 a1 = *(const float4*)(aRow + p0 + 4);
            av[0] = a0.x; av[1] = a0.y; av[2] = a0.z; av[3] = a0.w;
            av[4] = a1.x; av[5] = a1.y; av[6] = a1.z; av[7] = a1.w;
        }

        // dist = fl(fl(a+b) - 2*dot); ascending k + strict < = first-index
        #pragma unroll
        for (int i = 0; i < 8; ++i) {
            #pragma unroll
            for (int j = 0; j < 8; ++j) {
                float dist = __fsub_rn(__fadd_rn(av[i], bn[j]), 2.0f * acc[i][j]);
                int k = c * 256 + k0 + j;
                if (dist < best[i]) { best[i] = dist; bidx[i] = k; }
            }
        }
    }

    // ---- cross-thread argmin, 2-level (index tie-break => first-index) ----
    #pragma unroll
    for (int i = 0; i < 8; ++i) {
        redv[ty * 64 + p0 + i] = best[i];
        redi[ty * 64 + p0 + i] = bidx[i];
    }
    __syncthreads();

    {   // level 1: 4 groups scan 8 candidates each (all 256 threads active)
        const int p = t & 63, g = t >> 6;
        float bv = INFINITY; int bi = 0;
        #pragma unroll
        for (int x = g * 8; x < g * 8 + 8; ++x) {
            float v = redv[x * 64 + p];
            int ii = redi[x * 64 + p];
            if (v < bv || (v == bv && ii < bi)) { bv = v; bi = ii; }
        }
        r2v[g * 64 + p] = bv;
        r2i[g * 64 + p] = bi;
    }
    __syncthreads();

    if (t < 64) {   // level 2: combine 4 groups (ascending g)
        float bv = r2v[t];
        int bi = r2i[t];
        #pragma unroll
        for (int g = 1; g < 4; ++g) {
            float v = r2v[g * 64 + t];
            int ii = r2i[g * 64 + t];
            if (v < bv || (v == bv && ii < bi)) { bv = v; bi = ii; }
        }
        idxs[t] = bi;
        atomicAdd(&hist[bi], 1);
        out[OFF_CB + (size_t)blk * 64 + t] = (float)bi;
    }
    __syncthreads();   // idxs visible; redv/redi dead -> buf reusable as zqt

    // ---- gather winner rows into zqt[d][p], 2 threads per row ----
    if (t < 128) {
        const int p = t >> 1, half = t & 1;
        const int bi = idxs[p];
        const float4* wr4 = (const float4*)(wg + (size_t)bi * 64) + half * 8;
        #pragma unroll
        for (int q = 0; q < 8; ++q) {
            float4 v = wr4[q];
            int d = half * 32 + q * 4;
            zqt[(d + 0) * 64 + p] = v.x;
            zqt[(d + 1) * 64 + p] = v.y;
            zqt[(d + 2) * 64 + p] = v.z;
            zqt[(d + 3) * 64 + p] = v.w;
        }
    }

    // ---- encodings: one-hot rows, coalesced float4 nontemporal stores ----
    {
        nt4* enc = (nt4*)(out + OFF_ENC + (size_t)blk * 64 * NK);
        #pragma unroll
        for (int it = 0; it < 32; ++it) {
            int e = it * 256 + t;
            int r = e >> 7, cc = e & 127;
            int idx = idxs[r];
            nt4 v = {0.f, 0.f, 0.f, 0.f};
            if ((idx >> 2) == cc) v[idx & 3] = 1.0f;
            __builtin_nontemporal_store(v, &enc[(size_t)r * 128 + cc]);
        }
    }
    __syncthreads();   // zqt fully written

    // ---- z_q (straight-through) + loss partial, vectorized ----
    float lsum = 0.f;
    {
        float* zq = out + OFF_ZQ + (size_t)b * 262144 + (size_t)h * 64;
        #pragma unroll
        for (int it = 0; it < 4; ++it) {
            int f = it * 256 + t;            // 1024 float4s
            int d = f >> 4, pp = (f & 15) * 4;
            float4 zv = *(const float4*)(zt + d * 64 + pp);
            float4 qv = *(const float4*)(zqt + d * 64 + pp);
            nt4 o;
            float dx = __fsub_rn(qv.x, zv.x); lsum = __fadd_rn(lsum, __fmul_rn(dx, dx)); o.x = __fadd_rn(zv.x, dx);
            float dy = __fsub_rn(qv.y, zv.y); lsum = __fadd_rn(lsum, __fmul_rn(dy, dy)); o.y = __fadd_rn(zv.y, dy);
            float dz = __fsub_rn(qv.z, zv.z); lsum = __fadd_rn(lsum, __fmul_rn(dz, dz)); o.z = __fadd_rn(zv.z, dz);
            float dw = __fsub_rn(qv.w, zv.w); lsum = __fadd_rn(lsum, __fmul_rn(dw, dw)); o.w = __fadd_rn(zv.w, dw);
            __builtin_nontemporal_store(o, (nt4*)(zq + (size_t)d * 4096 + pp));
        }
    }
    #pragma unroll
    for (int off = 32; off > 0; off >>= 1)
        lsum += __shfl_down(lsum, off);
    if ((t & 63) == 0) wsum[t >> 6] = lsum;
    __syncthreads();
    if (t == 0) {
        float tot = (wsum[0] + wsum[1]) + (wsum[2] + wsum[3]);
        atomicAdd(lossAcc, (double)tot);
    }
}

__global__ __launch_bounds__(512) void vq_finalize(const int* __restrict__ hist,
                                                   const double* __restrict__ lossAcc,
                                                   float* __restrict__ out) {
    __shared__ float sh[512];
    const int t = threadIdx.x;
    float p = (float)hist[t] / (float)NPTS;   // exact: /2^17
    sh[t] = __fmul_rn(p, logf(__fadd_rn(p, 1e-10f)));
    __syncthreads();
    for (int s = 256; s > 0; s >>= 1) {
        if (t < s) sh[t] += sh[t + s];
        __syncthreads();
    }
    if (t == 0) {
        float m = (float)(*lossAcc / (double)NELEM);
        out[OFF_LOSS] = __fadd_rn(m, __fmul_rn(0.25f, m));
        out[OFF_PERP] = expf(-sh[0]);
    }
}

extern "C" void kernel_launch(void* const* d_in, const int* in_sizes, int n_in,
                              void* d_out, int out_size, void* d_ws, size_t ws_size,
                              hipStream_t stream) {
    const float* z = (const float*)d_in[0];
    const float* w = (const float*)d_in[1];
    float* out = (float*)d_out;
    int* hist = (int*)d_ws;
    double* lossAcc = (double*)((char*)d_ws + 2048);
    float* wT = (float*)((char*)d_ws + 4096);
    float* bnd = wT + 64 * 512;

    (void)hipMemsetAsync(d_ws, 0, 4096, stream);
    vq_prep<<<8, 256, 0, stream>>>(w, wT, bnd);
    vq_main<<<2048, 256, 0, stream>>>(z, w, wT, bnd, out, hist, lossAcc);
    vq_finalize<<<1, 512, 0, stream>>>(hist, lossAcc, out);
}

// Round 4
// 436.905 us; speedup vs baseline: 1.0823x; 1.0823x over previous
//
#include <hip/hip_runtime.h>
#include <math.h>

#define NK 512                      // N_EMB
#define NPTS (32*64*64)             // 131072 points
#define NELEM (32*64*64*64)         // 8388608 elements of z

// flat d_out offsets (return order: loss, z_q, perplexity, encodings, codebook)
#define OFF_LOSS 0
#define OFF_ZQ   1
#define OFF_PERP (1 + NELEM)
#define OFF_ENC  (2 + NELEM)
#define OFF_CB   (2 + NELEM + (size_t)NPTS * NK)

// ws layout: [0,2048) hist int[512] | [2048,2056) lossAcc double |
//            [4096, +128KB) wT f32[64][512] | then bnd f32[512]

// ---- prep: wT[d][k] = w[k][d]; bnd[k] = sum_d w[k][d]^2 (sequential d) ----
__global__ __launch_bounds__(256) void vq_prep(const float* __restrict__ wg,
                                               float* __restrict__ wT,
                                               float* __restrict__ bnd) {
    __shared__ float tl[64 * 65];
    const int t = threadIdx.x;
    const int kbase = blockIdx.x * 64;          // 8 blocks x 64 codes
    #pragma unroll
    for (int it = 0; it < 16; ++it) {
        int i = it * 256 + t;
        int k = i >> 6, d = i & 63;
        tl[k * 65 + d] = wg[(size_t)(kbase + k) * 64 + d];
    }
    __syncthreads();
    #pragma unroll
    for (int it = 0; it < 16; ++it) {
        int j = it * 256 + t;
        int d = j >> 6, kk = j & 63;
        wT[(size_t)d * 512 + kbase + kk] = tl[kk * 65 + d];
    }
    if (t < 64) {
        float s = 0.f;
        #pragma unroll 4
        for (int d = 0; d < 64; ++d) {
            float v = tl[t * 65 + d];
            s = __fadd_rn(s, __fmul_rn(v, v));
        }
        bnd[kbase + t] = s;
    }
}

// block = 64 points (one b,h row); 256 threads = 8 pgroups x 32 cgroups.
// w is NOT staged in LDS: per-d each wave reads a contiguous 256B window of
// wT (L2-resident, 8-way lane broadcast coalesced). LDS = zt(16K) + 16K
// overlay + ~3K -> 4 blocks/CU (16 waves/CU), chunk loop is barrier-free.
// launch_bounds(256,2): (256,4) forced VGPR=64 -> acc[8][8] spilled to
// scratch (FETCH +80MB). 120 VGPR still fits 4 waves/SIMD; LDS is limiter.
__global__ __launch_bounds__(256, 2) void vq_main(const float* __restrict__ zg,
                                                  const float* __restrict__ wg,
                                                  const float* __restrict__ wT,
                                                  const float* __restrict__ bndg,
                                                  float* __restrict__ out,
                                                  int* __restrict__ hist,
                                                  double* __restrict__ lossAcc) {
    const int t = threadIdx.x;
    const int blk = blockIdx.x;          // 2048 blocks = (b,h)
    const int b = blk >> 6;
    const int h = blk & 63;

    __shared__ __align__(16) float zt[64 * 64];    // zt[d][p]   (16 KB)
    __shared__ __align__(16) float buf[4096];      // 16 KB overlay
    __shared__ __align__(16) float r2v[256];       // level-2 argmin vals
    __shared__ int   r2i[256];                     // level-2 argmin idxs
    __shared__ float aRow[64];                     // ||z_p||^2
    __shared__ int   idxs[64];                     // winning code per point
    __shared__ float wsum[4];                      // per-wave loss partials

    float* redv = buf;                      // [32][64]  (phase 1)
    int*   redi = (int*)(buf + 2048);       // [32][64]  (phase 1)
    float* zqt  = buf;                      // [64][64]  (phase 2, after barrier)

    // ---- stage z tile: zt[c][w] = z[b,c,h,w]  (float2, conflict-free) ----
    {
        const size_t base = (size_t)b * 262144 + (size_t)h * 64;
        const int w2 = (t & 31) * 2;
        const int c0 = t >> 5;                       // 0..7
        #pragma unroll
        for (int c = c0; c < 64; c += 8) {
            float2 v = *(const float2*)(zg + base + (size_t)c * 4096 + w2);
            *(float2*)(zt + c * 64 + w2) = v;
        }
    }
    __syncthreads();

    // ---- a_p = sum_d z^2 (sequential d, mul+add — matches reference) ----
    if (t < 64) {
        float s = 0.f;
        for (int d = 0; d < 64; ++d) {
            float v = zt[d * 64 + t];
            s = __fadd_rn(s, __fmul_rn(v, v));
        }
        aRow[t] = s;
    }
    __syncthreads();

    const int tx = t & 7;      // point group: p = tx*8 + i   (i < 8)
    const int ty = t >> 3;     // code group:  k = c*256 + ty*8 + j  (j < 8)
    const int p0 = tx * 8;
    const int k0 = ty * 8;

    float best[8];
    int bidx[8];
    #pragma unroll
    for (int i = 0; i < 8; ++i) { best[i] = INFINITY; bidx[i] = 0; }

    const float* ztp = zt + p0;

    #pragma unroll
    for (int c = 0; c < 2; ++c) {
        float acc[8][8];
        #pragma unroll
        for (int i = 0; i < 8; ++i)
            #pragma unroll
            for (int j = 0; j < 8; ++j) acc[i][j] = 0.f;

        const float* wrow = wT + c * 256 + k0;       // stride 512 floats per d

        #pragma unroll 4
        for (int d = 0; d < 64; ++d) {
            float4 z0 = *(const float4*)(ztp + d * 64);
            float4 z1 = *(const float4*)(ztp + d * 64 + 4);
            float4 w0 = *(const float4*)(wrow + d * 512);
            float4 w1 = *(const float4*)(wrow + d * 512 + 4);
            const float zr[8] = {z0.x, z0.y, z0.z, z0.w, z1.x, z1.y, z1.z, z1.w};
            const float wr[8] = {w0.x, w0.y, w0.z, w0.w, w1.x, w1.y, w1.z, w1.w};
            #pragma unroll
            for (int i = 0; i < 8; ++i)
                #pragma unroll
                for (int j = 0; j < 8; ++j)
                    acc[i][j] = fmaf(zr[i], wr[j], acc[i][j]);
        }

        // code norms + point norms loaded late (keeps the hot loop lean)
        float bn[8];
        {
            const float4* bp = (const float4*)(bndg + c * 256 + k0);
            float4 b0 = bp[0], b1 = bp[1];
            bn[0] = b0.x; bn[1] = b0.y; bn[2] = b0.z; bn[3] = b0.w;
            bn[4] = b1.x; bn[5] = b1.y; bn[6] = b1.z; bn[7] = b1.w;
        }
        float av[8];
        {
            float4 a0 = *(const float4*)(aRow + p0);
            float4 a1 = *(const float4*)(aRow + p0 + 4);
            av[0] = a0.x; av[1] = a0.y; av[2] = a0.z; av[3] = a0.w;
            av[4] = a1.x; av[5] = a1.y; av[6] = a1.z; av[7] = a1.w;
        }

        // dist = fl(fl(a+b) - 2*dot); ascending k + strict < = first-index
        #pragma unroll
        for (int i = 0; i < 8; ++i) {
            #pragma unroll
            for (int j = 0; j < 8; ++j) {
                float dist = __fsub_rn(__fadd_rn(av[i], bn[j]), 2.0f * acc[i][j]);
                int k = c * 256 + k0 + j;
                if (dist < best[i]) { best[i] = dist; bidx[i] = k; }
            }
        }
    }

    // ---- cross-thread argmin, 2-level (index tie-break => first-index) ----
    #pragma unroll
    for (int i = 0; i < 8; ++i) {
        redv[ty * 64 + p0 + i] = best[i];
        redi[ty * 64 + p0 + i] = bidx[i];
    }
    __syncthreads();

    {   // level 1: 4 groups scan 8 candidates each (all 256 threads active)
        const int p = t & 63, g = t >> 6;
        float bv = INFINITY; int bi = 0;
        #pragma unroll
        for (int x = g * 8; x < g * 8 + 8; ++x) {
            float v = redv[x * 64 + p];
            int ii = redi[x * 64 + p];
            if (v < bv || (v == bv && ii < bi)) { bv = v; bi = ii; }
        }
        r2v[g * 64 + p] = bv;
        r2i[g * 64 + p] = bi;
    }
    __syncthreads();

    if (t < 64) {   // level 2: combine 4 groups (ascending g)
        float bv = r2v[t];
        int bi = r2i[t];
        #pragma unroll
        for (int g = 1; g < 4; ++g) {
            float v = r2v[g * 64 + t];
            int ii = r2i[g * 64 + t];
            if (v < bv || (v == bv && ii < bi)) { bv = v; bi = ii; }
        }
        idxs[t] = bi;
        atomicAdd(&hist[bi], 1);
        out[OFF_CB + (size_t)blk * 64 + t] = (float)bi;
    }
    __syncthreads();   // idxs visible; redv/redi dead -> buf reusable as zqt

    // ---- gather winner rows into zqt[d][p], 2 threads per row ----
    if (t < 128) {
        const int p = t >> 1, half = t & 1;
        const int bi = idxs[p];
        const float4* wr4 = (const float4*)(wg + (size_t)bi * 64) + half * 8;
        #pragma unroll
        for (int q = 0; q < 8; ++q) {
            float4 v = wr4[q];
            int d = half * 32 + q * 4;
            zqt[(d + 0) * 64 + p] = v.x;
            zqt[(d + 1) * 64 + p] = v.y;
            zqt[(d + 2) * 64 + p] = v.z;
            zqt[(d + 3) * 64 + p] = v.w;
        }
    }

    // ---- encodings: one-hot rows, coalesced float4 (plain stores) ----
    {
        float4* enc = (float4*)(out + OFF_ENC + (size_t)blk * 64 * NK);
        #pragma unroll
        for (int it = 0; it < 32; ++it) {
            int e = it * 256 + t;
            int r = e >> 7, cc = e & 127;
            int idx = idxs[r];
            float4 v = make_float4(0.f, 0.f, 0.f, 0.f);
            if ((idx >> 2) == cc) ((float*)&v)[idx & 3] = 1.0f;
            enc[(size_t)r * 128 + cc] = v;
        }
    }
    __syncthreads();   // zqt fully written

    // ---- z_q (straight-through) + loss partial, vectorized ----
    float lsum = 0.f;
    {
        float* zq = out + OFF_ZQ + (size_t)b * 262144 + (size_t)h * 64;
        #pragma unroll
        for (int it = 0; it < 4; ++it) {
            int f = it * 256 + t;            // 1024 float4s
            int d = f >> 4, pp = (f & 15) * 4;
            float4 zv = *(const float4*)(zt + d * 64 + pp);
            float4 qv = *(const float4*)(zqt + d * 64 + pp);
            float4 o;
            float dx = __fsub_rn(qv.x, zv.x); lsum = __fadd_rn(lsum, __fmul_rn(dx, dx)); o.x = __fadd_rn(zv.x, dx);
            float dy = __fsub_rn(qv.y, zv.y); lsum = __fadd_rn(lsum, __fmul_rn(dy, dy)); o.y = __fadd_rn(zv.y, dy);
            float dz = __fsub_rn(qv.z, zv.z); lsum = __fadd_rn(lsum, __fmul_rn(dz, dz)); o.z = __fadd_rn(zv.z, dz);
            float dw = __fsub_rn(qv.w, zv.w); lsum = __fadd_rn(lsum, __fmul_rn(dw, dw)); o.w = __fadd_rn(zv.w, dw);
            *(float4*)(zq + (size_t)d * 4096 + pp) = o;
        }
    }
    #pragma unroll
    for (int off = 32; off > 0; off >>= 1)
        lsum += __shfl_down(lsum, off);
    if ((t & 63) == 0) wsum[t >> 6] = lsum;
    __syncthreads();
    if (t == 0) {
        float tot = (wsum[0] + wsum[1]) + (wsum[2] + wsum[3]);
        atomicAdd(lossAcc, (double)tot);
    }
}

__global__ __launch_bounds__(512) void vq_finalize(const int* __restrict__ hist,
                                                   const double* __restrict__ lossAcc,
                                                   float* __restrict__ out) {
    __shared__ float sh[512];
    const int t = threadIdx.x;
    float p = (float)hist[t] / (float)NPTS;   // exact: /2^17
    sh[t] = __fmul_rn(p, logf(__fadd_rn(p, 1e-10f)));
    __syncthreads();
    for (int s = 256; s > 0; s >>= 1) {
        if (t < s) sh[t] += sh[t + s];
        __syncthreads();
    }
    if (t == 0) {
        float m = (float)(*lossAcc / (double)NELEM);
        out[OFF_LOSS] = __fadd_rn(m, __fmul_rn(0.25f, m));
        out[OFF_PERP] = expf(-sh[0]);
    }
}

extern "C" void kernel_launch(void* const* d_in, const int* in_sizes, int n_in,
                              void* d_out, int out_size, void* d_ws, size_t ws_size,
                              hipStream_t stream) {
    const float* z = (const float*)d_in[0];
    const float* w = (const float*)d_in[1];
    float* out = (float*)d_out;
    int* hist = (int*)d_ws;
    double* lossAcc = (double*)((char*)d_ws + 2048);
    float* wT = (float*)((char*)d_ws + 4096);
    float* bnd = wT + 64 * 512;

    (void)hipMemsetAsync(d_ws, 0, 4096, stream);
    vq_prep<<<8, 256, 0, stream>>>(w, wT, bnd);
    vq_main<<<2048, 256, 0, stream>>>(z, w, wT, bnd, out, hist, lossAcc);
    vq_finalize<<<1, 512, 0, stream>>>(hist, lossAcc, out);
}